// Round 4
// baseline (1429.066 us; speedup 1.0000x reference)
//
#include <hip/hip_runtime.h>

// CRF log-likelihood. B=256, L=1024, D=126, T=128.
// R7: SINGLE-WAVE recursion, zero barriers. R4-R6 showed step time is a
// ~500-600cyc fixed cost (barrier + cross-wave LDS round trip) insensitive
// to work tuning (938/1046/1550 cyc across 8/4/16-wave variants). Fix: one
// wave per batch (grid 256x64, 1 wave/CU). Lane i owns outputs {i, 64+i};
// BOTH transition rows live in VGPRs as k-paired v2f (tLo[64]+tHi[64] =
// 256 VGPRs; __launch_bounds__(64,1) allows ~512). alpha (128f) sits in
// two 64f LDS buffers, read per step as 32 UNIFORM-ADDRESS ds_read_b128
// (same-address = broadcast, conflict-free). Accumulation is in-lane ->
// no DPP reduce, no select, no barrier; LDS ordering is wave-internal
// (compiler lgkmcnt). Rebase max is free: all lanes read all of alpha, so
// a per-lane fmax over the broadcast data IS the global max (uniform).
// FMA as v_pk_fma_f32 (128/step = 256 issue cyc). Logits prefetched from
// global 4 steps ahead into rotating regs (2 coalesced dwords/step) -- no
// Lbuf staging at all.

typedef float v2f __attribute__((ext_vector_type(2)));

#define LOG2E   1.4426950408889634f
#define LN2     0.6931471805599453f

constexpr int Bc = 256, Lc = 1024, Dc = 126, Tc = 128;

#if __has_builtin(__builtin_amdgcn_exp2f)
#define FEXP2(x) __builtin_amdgcn_exp2f(x)
#else
#define FEXP2(x) exp2f(x)
#endif
#if __has_builtin(__builtin_amdgcn_logf)
#define FLOG2(x) __builtin_amdgcn_logf(x)
#else
#define FLOG2(x) log2f(x)
#endif

__device__ __forceinline__ v2f pkfma(v2f a, v2f b, v2f c) {
#if __has_builtin(__builtin_elementwise_fma)
    return __builtin_elementwise_fma(a, b, c);
#else
    v2f r; r.x = fmaf(a.x, b.x, c.x); r.y = fmaf(a.y, b.y, c.y); return r;
#endif
}

__global__ __launch_bounds__(64, 1) void crf_fwd_kernel(
    const float* __restrict__ x,      // [B, L, D]
    const float* __restrict__ trans,  // [T, T] row-major
    const int*   __restrict__ x_len,  // [B]
    const int*   __restrict__ tag,    // [B, L]
    float*       __restrict__ out)    // [B]
{
    __shared__ __align__(16) float EA[2][64];   // alpha[0..63], dbuf
    __shared__ __align__(16) float EB[2][64];   // alpha[64..127], dbuf

    const int b = blockIdx.x;
    const int i = threadIdx.x;           // lane 0..63
    const int len = x_len[b];

    const float* xb = x   + (size_t)b * Lc * Dc;
    const int*   tb = tag + (size_t)b * Lc;

    const bool hiOK = (64 + i) < Dc;     // lanes 0..61 have a valid high state

    // ---- transition rows i and 64+i, exp'd, packed by k-pairs ----
    // tLo[kk] = (expT[i][2kk], expT[i][2kk+1]), kk = 0..63 (all 128 k)
    v2f tLo[64], tHi[64];
    {
        const float4* rl = reinterpret_cast<const float4*>(trans + i * Tc);
        const float4* rh = reinterpret_cast<const float4*>(trans + (64 + i) * Tc);
#pragma unroll
        for (int c = 0; c < 32; ++c) {
            float4 a = rl[c];
            tLo[2*c]   = (v2f){FEXP2(a.x * LOG2E), FEXP2(a.y * LOG2E)};
            tLo[2*c+1] = (v2f){FEXP2(a.z * LOG2E), FEXP2(a.w * LOG2E)};
            float4 h = rh[c];
            tHi[2*c]   = (v2f){FEXP2(h.x * LOG2E), FEXP2(h.y * LOG2E)};
            tHi[2*c+1] = (v2f){FEXP2(h.z * LOG2E), FEXP2(h.w * LOG2E)};
        }
    }

    // ---- init alpha = delta(START=126): bufB[62] = 1 ----
    EA[0][i] = 0.0f;
    EB[0][i] = (i == 62) ? 1.0f : 0.0f;

    // ---- prologue: P for step 0; pf[1..3] = logits of steps 1..3 ----
    v2f P, pf[4];
    {
        float lx = xb[i];
        float hx = xb[hiOK ? (64 + i) : 0];
        P.x = FEXP2(lx * LOG2E);
        P.y = hiOK ? FEXP2(hx * LOG2E) : 0.0f;
    }
#pragma unroll
    for (int c = 1; c < 4; ++c) {
        int ls = (c < len) ? c : (len - 1);
        const float* row = xb + (size_t)ls * Dc;
        pf[c].x = row[i];
        pf[c].y = row[hiOK ? (64 + i) : 0];
    }
    pf[0] = pf[1];  // placeholder; overwritten in body 0 before use

    int Mint = 0;                        // exact base-2 shift accumulator
    const int len4 = (len + 3) & ~3;

    // ---- forward recursion: no barriers, wave-internal LDS ordering ----
    for (int l = 0; l < len4; l += 4) {
#pragma unroll
        for (int c = 0; c < 4; ++c) {
            const int  p   = c & 1;          // (l+c)&1 since l%4==0
            const bool act = (l + c) < len;  // wave-uniform tail guard

            // prefetch logits for step l+c+4 into pf[c] (old value already
            // consumed in body c-1; clamped address, consumed ~3-4 steps
            // later => ~1300+ cyc of latency cover)
            {
                int ls = l + c + 4; if (ls > len - 1) ls = len - 1;
                const float* row = xb + (size_t)ls * Dc;
                pf[c].x = row[i];
                pf[c].y = row[hiOK ? (64 + i) : 0];
            }

            // matvec: 32 broadcast b128 reads, 128 pk-FMA, in-lane accum
            const float* A = EA[p];
            const float* Bp = EB[p];
            v2f aL0 = {0.f,0.f}, aL1 = {0.f,0.f}, aH0 = {0.f,0.f}, aH1 = {0.f,0.f};
            float mx = 0.0f;
#pragma unroll
            for (int q = 0; q < 16; ++q) {
                float4 va = *reinterpret_cast<const float4*>(A + 4*q);
                v2f v01 = {va.x, va.y}, v23 = {va.z, va.w};
                aL0 = pkfma(tLo[2*q],   v01, aL0);
                aL1 = pkfma(tLo[2*q+1], v23, aL1);
                aH0 = pkfma(tHi[2*q],   v01, aH0);
                aH1 = pkfma(tHi[2*q+1], v23, aH1);
                if (c == 3) mx = fmaxf(mx, fmaxf(fmaxf(va.x, va.y), fmaxf(va.z, va.w)));
            }
#pragma unroll
            for (int q = 0; q < 16; ++q) {
                float4 vb = *reinterpret_cast<const float4*>(Bp + 4*q);
                v2f v01 = {vb.x, vb.y}, v23 = {vb.z, vb.w};
                aL0 = pkfma(tLo[32+2*q],   v01, aL0);
                aL1 = pkfma(tLo[32+2*q+1], v23, aL1);
                aH0 = pkfma(tHi[32+2*q],   v01, aH0);
                aH1 = pkfma(tHi[32+2*q+1], v23, aH1);
                if (c == 3) mx = fmaxf(mx, fmaxf(fmaxf(vb.x, vb.y), fmaxf(vb.z, vb.w)));
            }
            float outLo = (aL0.x + aL0.y) + (aL1.x + aL1.y);
            float outHi = (aH0.x + aH0.y) + (aH1.x + aH1.y);

            // rebase every 4th step: mx is the EXACT global max (uniform
            // broadcast data), no cross-lane reduce needed
            float R = 1.0f;
            if (c == 3 && act) {
                int ebq = (__float_as_int(mx) >> 23) & 0xFF;
                R = __int_as_float((254 - ebq) << 23);   // 2^(127-ebq)
                Mint += ebq - 127;
            }

            if (act) {
                EA[p ^ 1][i] = outLo * P.x * R;
                EB[p ^ 1][i] = outHi * P.y * R;
            }

            // emission factors for the next step (pf loaded >=3 steps ago)
            v2f nl = pf[(c + 1) & 3];
            P.x = FEXP2(nl.x * LOG2E);
            P.y = hiOK ? FEXP2(nl.y * LOG2E) : 0.0f;
        }
    }
    const int pfb = len & 1;             // final alpha buffer

    // ---- partition = ln2 * (Mint + log2(sum_k exp(t_stop_k) * alpha_k)) ----
    float part;
    {
        float aAv = EA[pfb][i];
        float aBv = EB[pfb][i];
        float sA = FEXP2(trans[(Tc-1) * Tc + i]        * LOG2E);
        float sB = FEXP2(trans[(Tc-1) * Tc + 64 + i]   * LOG2E);
        float ps = sA * aAv + sB * aBv;
#pragma unroll
        for (int off = 1; off < 64; off <<= 1)
            ps += __shfl_xor(ps, off, 64);
        part = LN2 * ((float)Mint + FLOG2(ps));
    }

    // ---- score: emission + pairwise transitions (cooperative over l) ----
    float acc = 0.0f;
    for (int l2 = i; l2 < len; l2 += 64) {
        int   tg = tb[l2];
        float tr = (l2 == 0) ? trans[tg * Tc + (Tc - 2)]
                             : trans[tg * Tc + tb[l2 - 1]];
        acc += xb[(size_t)l2 * Dc + tg] + tr;
    }
#pragma unroll
    for (int off = 1; off < 64; off <<= 1)
        acc += __shfl_xor(acc, off, 64);

    if (i == 0) {
        float sc = acc + trans[(Tc-1) * Tc + tb[len - 1]];   // STOP transition
        out[b] = sc - part;
    }
}

extern "C" void kernel_launch(void* const* d_in, const int* in_sizes, int n_in,
                              void* d_out, int out_size, void* d_ws, size_t ws_size,
                              hipStream_t stream) {
    const float* x     = (const float*)d_in[0];
    const float* trans = (const float*)d_in[1];
    // d_in[2] = x_mask (redundant with x_len)
    const int*   x_len = (const int*)d_in[3];
    const int*   tag   = (const int*)d_in[4];
    float*       out   = (float*)d_out;

    crf_fwd_kernel<<<Bc, 64, 0, stream>>>(x, trans, x_len, tag, out);
}

// Round 5
// 545.398 us; speedup vs baseline: 2.6202x; 2.6202x over previous
//
#include <hip/hip_runtime.h>

// CRF log-likelihood. B=256, L=1024, D=126, T=128. One block/batch, 512 thr.
// R8 = R4-structure (8 waves, thread = 4 outputs x 8 inputs, DPP ring
// reduce over 16-lane rows) with the step stripped to the bone:
//  - NO Lbuf: logits prefetched global->register 4 steps ahead into
//    statically-indexed rotating slots (no LDS logit read, no staging).
//  - E layout idx(k)=4*sig(k>>2)+(k&3), sig(q)=q^(q>>3): the 16-lane
//    2x b128 read pattern hits every bank-quad exactly 2x (2-way = free,
//    m136) and quad writes are conflict-free. (R4's xor swizzle was
//    structurally >=2-way: 9.2M conflicts.)
//  - After the ring reduce EVERY lane holds all 4 sums -> lane o==0
//    writes one ds_write_b128 (quad jg contiguous in sig-layout); the
//    select cascade is gone.
//  - Emission exp2 applied at the write; inputs loaded ~4 steps early.
// One raw lgkmcnt(0)+s_barrier per step (vmcnt rides across barriers).
// R7 lesson: >256 addressable VGPRs spills (single-wave design dead);
// 2 waves/SIMD is the proven overlap point.

typedef float v2f __attribute__((ext_vector_type(2)));

#define NEGV  (-10000.0f)
#define LOG2E 1.4426950408889634f
#define LN2   0.6931471805599453f

constexpr int Bc = 256, Lc = 1024, Dc = 126, Tc = 128;

#if __has_builtin(__builtin_amdgcn_exp2f)
#define FEXP2(x) __builtin_amdgcn_exp2f(x)
#else
#define FEXP2(x) exp2f(x)
#endif
#if __has_builtin(__builtin_amdgcn_logf)
#define FLOG2(x) __builtin_amdgcn_logf(x)
#else
#define FLOG2(x) log2f(x)
#endif

// DPP row_ror:N within 16-lane rows (ring-reduce: after ror 1,2,4,8 every
// lane holds the full row total).
#if __has_builtin(__builtin_amdgcn_mov_dpp)
#define DPPF(x, ctrl) __int_as_float(__builtin_amdgcn_mov_dpp(__float_as_int(x), (ctrl), 0xF, 0xF, true))
#define ROR1(x) DPPF(x, 0x121)
#define ROR2(x) DPPF(x, 0x122)
#define ROR4(x) DPPF(x, 0x124)
#define ROR8(x) DPPF(x, 0x128)
#else
#define ROR1(x) __shfl_xor((x), 1, 64)
#define ROR2(x) __shfl_xor((x), 2, 64)
#define ROR4(x) __shfl_xor((x), 4, 64)
#define ROR8(x) __shfl_xor((x), 8, 64)
#endif

#define STEP_BARRIER() asm volatile("s_waitcnt lgkmcnt(0)\n\ts_barrier" ::: "memory")

__device__ __forceinline__ int SIG(int q) { return q ^ (q >> 3); }   // bijective on [0,32)
__device__ __forceinline__ int Fmap(int k) { return 4 * SIG(k >> 2) + (k & 3); }

__global__ __launch_bounds__(512, 1) void crf_fwd_kernel(
    const float* __restrict__ x,      // [B, L, D]
    const float* __restrict__ trans,  // [T, T] row-major
    const int*   __restrict__ x_len,  // [B]
    const int*   __restrict__ tag,    // [B, L]
    float*       __restrict__ out)    // [B]
{
    __shared__ __align__(16) float E[2][Tc];   // rebased exp(alpha), dbuf, sig-permuted
    __shared__ float red[12];                  // epilogue reductions

    const int b   = blockIdx.x;
    const int tid = threadIdx.x;
    const int w   = tid >> 6;             // wave 0..7
    const int l6  = tid & 63;
    const int o   = l6 & 15;              // k-octet: k in [8o, 8o+8)
    const int jg  = (w << 2) | (l6 >> 4); // j-group 0..31: j in [4jg, 4jg+4)
    const int len = x_len[b];             // block-uniform

    const float* xb = x   + (size_t)b * Lc * Dc;
    const int*   tb = tag + (size_t)b * Lc;

    const int  f0 = 4 * SIG(2 * o);       // E read: k = 8o..8o+3
    const int  f1 = 4 * SIG(2 * o + 1);   //         k = 8o+4..8o+7
    const int  wq = 4 * SIG(jg);          // E write: quad jg (b128)
    const bool hiBad = (jg == 31);        // j=126,127 have no logits (NEG pad)

    // ---- constant weights: treg[g][c] = exp(trans[4jg+g, 8o+c]) ----
    float treg[4][8];
#pragma unroll
    for (int g = 0; g < 4; ++g) {
        const float4* tp = reinterpret_cast<const float4*>(trans + (4*jg + g) * Tc + 8*o);
        float4 t0 = tp[0], t1 = tp[1];
        treg[g][0] = FEXP2(t0.x * LOG2E); treg[g][1] = FEXP2(t0.y * LOG2E);
        treg[g][2] = FEXP2(t0.z * LOG2E); treg[g][3] = FEXP2(t0.w * LOG2E);
        treg[g][4] = FEXP2(t1.x * LOG2E); treg[g][5] = FEXP2(t1.y * LOG2E);
        treg[g][6] = FEXP2(t1.z * LOG2E); treg[g][7] = FEXP2(t1.w * LOG2E);
    }

    // ---- init E = delta(START=126) ----
    if (tid < Tc) E[0][Fmap(tid)] = (tid == Tc - 2) ? 1.0f : 0.0f;
    __syncthreads();

    // ---- logit prefetch: thread covers j = 4jg..4jg+3 of row l (2x v2f,
    // 8B-aligned; jg==31's high pair is the NEG pad, never loaded) ----
#define LOADP(LS, A, B2) {                                              \
        int _s = (LS); if (_s > len - 1) _s = len - 1;                  \
        const float* _r = xb + (size_t)_s * Dc + 4 * jg;                \
        A  = *reinterpret_cast<const v2f*>(_r);                         \
        B2 = hiBad ? (v2f){NEGV, NEGV}                                  \
                   : *reinterpret_cast<const v2f*>(_r + 2); }

    v2f Pa, Pb;                            // emission factors for current step
    {
        v2f a, b2; LOADP(0, a, b2);
        Pa = (v2f){FEXP2(a.x * LOG2E),  FEXP2(a.y * LOG2E)};
        Pb = (v2f){FEXP2(b2.x * LOG2E), FEXP2(b2.y * LOG2E)};
    }
    v2f pA0, pB0, pA1, pB1, pA2, pB2, pA3, pB3;   // slot s: logits of step l+1 where l%4==s-1... (ring)
    LOADP(1, pA1, pB1); LOADP(2, pA2, pB2); LOADP(3, pA3, pB3);
    pA0 = pA1; pB0 = pB1;                 // placeholder; refilled at c=0 before use

    int Mint = 0;                          // exact base-2 shift accumulator
    const int len4 = (len + 3) & ~3;

    // ---- forward recursion: one raw barrier/step; 4-deep static unroll ----
#define BODY(C, PA_LD, PB_LD, PA_NX, PB_NX) {                                   \
        const int  l   = l4 + (C);                                              \
        const bool act = l < len;         /* block-uniform tail guard */        \
        const int  p   = (C) & 1;                                               \
        LOADP(l + 4, PA_LD, PB_LD);       /* for step l+4, consumed @ l+3 */    \
        const float* Ep = E[p];                                                 \
        float4 ea = *reinterpret_cast<const float4*>(Ep + f0);                  \
        float4 eb = *reinterpret_cast<const float4*>(Ep + f1);                  \
        float a0 = treg[0][0]*ea.x, a1 = treg[1][0]*ea.x,                       \
              a2 = treg[2][0]*ea.x, a3 = treg[3][0]*ea.x;                       \
        a0=fmaf(treg[0][1],ea.y,a0); a1=fmaf(treg[1][1],ea.y,a1);               \
        a2=fmaf(treg[2][1],ea.y,a2); a3=fmaf(treg[3][1],ea.y,a3);               \
        a0=fmaf(treg[0][2],ea.z,a0); a1=fmaf(treg[1][2],ea.z,a1);               \
        a2=fmaf(treg[2][2],ea.z,a2); a3=fmaf(treg[3][2],ea.z,a3);               \
        a0=fmaf(treg[0][3],ea.w,a0); a1=fmaf(treg[1][3],ea.w,a1);               \
        a2=fmaf(treg[2][3],ea.w,a2); a3=fmaf(treg[3][3],ea.w,a3);               \
        a0=fmaf(treg[0][4],eb.x,a0); a1=fmaf(treg[1][4],eb.x,a1);               \
        a2=fmaf(treg[2][4],eb.x,a2); a3=fmaf(treg[3][4],eb.x,a3);               \
        a0=fmaf(treg[0][5],eb.y,a0); a1=fmaf(treg[1][5],eb.y,a1);               \
        a2=fmaf(treg[2][5],eb.y,a2); a3=fmaf(treg[3][5],eb.y,a3);               \
        a0=fmaf(treg[0][6],eb.z,a0); a1=fmaf(treg[1][6],eb.z,a1);               \
        a2=fmaf(treg[2][6],eb.z,a2); a3=fmaf(treg[3][6],eb.z,a3);               \
        a0=fmaf(treg[0][7],eb.w,a0); a1=fmaf(treg[1][7],eb.w,a1);               \
        a2=fmaf(treg[2][7],eb.w,a2); a3=fmaf(treg[3][7],eb.w,a3);               \
        a0 += ROR1(a0); a1 += ROR1(a1); a2 += ROR1(a2); a3 += ROR1(a3);         \
        a0 += ROR2(a0); a1 += ROR2(a1); a2 += ROR2(a2); a3 += ROR2(a3);         \
        a0 += ROR4(a0); a1 += ROR4(a1); a2 += ROR4(a2); a3 += ROR4(a3);         \
        a0 += ROR8(a0); a1 += ROR8(a1); a2 += ROR8(a2); a3 += ROR8(a3);         \
        float R = 1.0f;                                                         \
        if ((C) == 3 && act) {            /* rebase: exact pow2, k=2 mod 4 */   \
            float mx = fmaxf(ea.z, eb.z);                                       \
            mx = fmaxf(mx, ROR1(mx)); mx = fmaxf(mx, ROR2(mx));                 \
            mx = fmaxf(mx, ROR4(mx)); mx = fmaxf(mx, ROR8(mx));                 \
            int ebq = (__float_as_int(mx) >> 23) & 0xFF;                        \
            R = __int_as_float((254 - ebq) << 23);                              \
            Mint += ebq - 127;                                                  \
        }                                                                       \
        if (act && o == 0)                /* all lanes hold a0..a3 post-ring */ \
            *reinterpret_cast<float4*>(&E[p ^ 1][wq]) =                         \
                make_float4(a0 * Pa.x * R, a1 * Pa.y * R,                       \
                            a2 * Pb.x * R, a3 * Pb.y * R);                      \
        Pa = (v2f){FEXP2(PA_NX.x * LOG2E), FEXP2(PA_NX.y * LOG2E)};             \
        Pb = (v2f){FEXP2(PB_NX.x * LOG2E), FEXP2(PB_NX.y * LOG2E)};             \
        STEP_BARRIER();                                                         \
    }

    for (int l4 = 0; l4 < len4; l4 += 4) {
        BODY(0, pA0, pB0, pA1, pB1)
        BODY(1, pA1, pB1, pA2, pB2)
        BODY(2, pA2, pB2, pA3, pB3)
        BODY(3, pA3, pB3, pA0, pB0)
    }
#undef BODY
#undef LOADP
    const int pf = len & 1;               // final E buffer

    // ---- score: emission + pairwise transitions (cooperative over l) ----
    float acc = 0.f;
    for (int l = tid; l < len; l += 512) {
        int   tg = tb[l];
        float tr = (l == 0) ? trans[tg * Tc + (Tc - 2)]
                            : trans[tg * Tc + tb[l - 1]];
        acc += xb[(size_t)l * Dc + tg] + tr;
    }
#pragma unroll
    for (int off = 1; off < 64; off <<= 1)
        acc += __shfl_xor(acc, off, 64);
    if (l6 == 0) red[w] = acc;

    // ---- partition = ln2 * (Mint + log2(sum_k exp(t_stop_k) * E_k)) ----
    if (w == 0) {
        int k0i = l6, k1i = 64 + l6;
        float p0 = FEXP2(trans[(Tc-1) * Tc + k0i] * LOG2E) * E[pf][Fmap(k0i)];
        float p1 = FEXP2(trans[(Tc-1) * Tc + k1i] * LOG2E) * E[pf][Fmap(k1i)];
        float ps = p0 + p1;
#pragma unroll
        for (int off = 1; off < 64; off <<= 1)
            ps += __shfl_xor(ps, off, 64);
        if (l6 == 0) red[8] = LN2 * ((float)Mint + FLOG2(ps));
    }
    __syncthreads();

    if (tid == 0) {
        float sc = trans[(Tc-1) * Tc + tb[len - 1]];   // STOP transition
#pragma unroll
        for (int i = 0; i < 8; ++i) sc += red[i];
        out[b] = sc - red[8];
    }
}

extern "C" void kernel_launch(void* const* d_in, const int* in_sizes, int n_in,
                              void* d_out, int out_size, void* d_ws, size_t ws_size,
                              hipStream_t stream) {
    const float* x     = (const float*)d_in[0];
    const float* trans = (const float*)d_in[1];
    // d_in[2] = x_mask (redundant with x_len)
    const int*   x_len = (const int*)d_in[3];
    const int*   tag   = (const int*)d_in[4];
    float*       out   = (float*)d_out;

    crf_fwd_kernel<<<Bc, 512, 0, stream>>>(x, trans, x_len, tag, out);
}